// Round 6
// baseline (494.259 us; speedup 1.0000x reference)
//
#include <hip/hip_runtime.h>
#include <math.h>

// Problem constants (B=16, H=W=56, C=512, window=7)
#define NTOK_PER_B 3136
#define NBATCH 16
#define M_TOK (NTOK_PER_B * NBATCH)   // 50176
#define CDIM 512
#define NWIN 448                      // 3136 / 7
#define SCALE 0.04419417382415922f    // 512^-0.5

typedef _Float16 half8 __attribute__((ext_vector_type(8)));
typedef float f32x4 __attribute__((ext_vector_type(4)));

#define GLOAD16(g, l) __builtin_amdgcn_global_load_lds( \
    (const __attribute__((address_space(1))) void*)(g),  \
    (__attribute__((address_space(3))) void*)(l), 16, 0, 0)

__device__ __forceinline__ float wave_sum64(float s) {
    #pragma unroll
    for (int o = 32; o >= 1; o >>= 1) s += __shfl_xor(s, o, 64);
    return s;
}

// ---------------------------------------------------------------------------
// x (fp32) -> fp16, 8 elems/thread
// ---------------------------------------------------------------------------
__global__ __launch_bounds__(256) void cvt_f32_f16(
    const float* __restrict__ x, _Float16* __restrict__ y)
{
    const size_t i = ((size_t)blockIdx.x * 256 + threadIdx.x) * 8;
    const float4 a = *(const float4*)(x + i);
    const float4 b = *(const float4*)(x + i + 4);
    half8 o;
    o[0] = (_Float16)a.x; o[1] = (_Float16)a.y; o[2] = (_Float16)a.z; o[3] = (_Float16)a.w;
    o[4] = (_Float16)b.x; o[5] = (_Float16)b.y; o[6] = (_Float16)b.z; o[7] = (_Float16)b.w;
    *(half8*)(y + i) = o;
}

// ---------------------------------------------------------------------------
// W [K=512][N=512] fp32 -> Wt [N][K] fp16 (transposed), 3 matrices via z
// ---------------------------------------------------------------------------
__global__ __launch_bounds__(256) void cvt_w_t(
    const float* __restrict__ w0, const float* __restrict__ w1,
    const float* __restrict__ w2, _Float16* __restrict__ wt)
{
    const float* w = (blockIdx.z == 0) ? w0 : ((blockIdx.z == 1) ? w1 : w2);
    _Float16* o = wt + (size_t)blockIdx.z * CDIM * CDIM;
    __shared__ float tile[32][33];
    const int tx = threadIdx.x & 31;
    const int ty = threadIdx.x >> 5;          // 0..7
    const int k0 = blockIdx.x * 32;
    const int n0 = blockIdx.y * 32;
    #pragma unroll
    for (int r = 0; r < 32; r += 8)
        tile[ty + r][tx] = w[(size_t)(k0 + ty + r) * CDIM + n0 + tx];
    __syncthreads();
    #pragma unroll
    for (int r = 0; r < 32; r += 8)
        o[(size_t)(n0 + ty + r) * CDIM + k0 + tx] = (_Float16)tile[tx][ty + r];
}

// ---------------------------------------------------------------------------
// GEMM (R2-measured structure, byte-identical): out[z] = xh @ Wt[z]^T + bias.
// 128x128 tile, BK=32, 4 waves (2x2), 4x4 16x16x32 MFMA frags.
// grid = (392, 4, 3)
// ---------------------------------------------------------------------------
__global__ __launch_bounds__(256) void qkv_gemm_f16(
    const _Float16* __restrict__ A,
    const _Float16* __restrict__ Wt,
    const float* __restrict__ b0, const float* __restrict__ b1,
    const float* __restrict__ b2,
    _Float16* __restrict__ out)
{
    const int z = blockIdx.z;
    const _Float16* W = Wt + (size_t)z * CDIM * CDIM;
    const float* bias = (z == 0) ? b0 : ((z == 1) ? b1 : b2);
    _Float16* O = out + (size_t)z * (size_t)M_TOK * CDIM;

    __shared__ _Float16 As[128 * 32];   // row-major [row][k]
    __shared__ _Float16 Bs[128 * 32];   // row-major [n][k]

    const int t    = threadIdx.x;
    const int lane = t & 63;
    const int wid  = t >> 6;
    const int wrow = (wid >> 1) * 64;
    const int wcol = (wid & 1) * 64;
    const int row0 = blockIdx.x * 128;
    const int col0 = blockIdx.y * 128;

    // staging: chunk c (0..511) -> LDS byte c*16, row c/4, k-slot (c%4)*8
    const _Float16* aSrc0 = A + (size_t)(row0 + (t >> 2)) * CDIM + (t & 3) * 8;
    const _Float16* aSrc1 = aSrc0 + (size_t)64 * CDIM;
    const _Float16* bSrc0 = W + (size_t)(col0 + (t >> 2)) * CDIM + (t & 3) * 8;
    const _Float16* bSrc1 = bSrc0 + (size_t)64 * CDIM;
    _Float16* aDst0 = As + t * 8;
    _Float16* aDst1 = As + (t + 256) * 8;
    _Float16* bDst0 = Bs + t * 8;
    _Float16* bDst1 = Bs + (t + 256) * 8;

    f32x4 acc[4][4];
    #pragma unroll
    for (int m = 0; m < 4; ++m)
        #pragma unroll
        for (int n = 0; n < 4; ++n)
            acc[m][n] = (f32x4){0.f, 0.f, 0.f, 0.f};

    const int fr  = lane & 15;
    const int q8o = (lane >> 4) * 8;

    for (int k0 = 0; k0 < CDIM; k0 += 32) {
        GLOAD16(aSrc0 + k0, aDst0);
        GLOAD16(aSrc1 + k0, aDst1);
        GLOAD16(bSrc0 + k0, bDst0);
        GLOAD16(bSrc1 + k0, bDst1);
        __syncthreads();   // drains vmcnt: LDS tile ready

        half8 af[4], bf[4];
        #pragma unroll
        for (int m = 0; m < 4; ++m)
            af[m] = *(const half8*)(As + (wrow + m * 16 + fr) * 32 + q8o);
        #pragma unroll
        for (int n = 0; n < 4; ++n)
            bf[n] = *(const half8*)(Bs + (wcol + n * 16 + fr) * 32 + q8o);
        #pragma unroll
        for (int m = 0; m < 4; ++m)
            #pragma unroll
            for (int n = 0; n < 4; ++n)
                acc[m][n] = __builtin_amdgcn_mfma_f32_16x16x32_f16(
                    af[m], bf[n], acc[m][n], 0, 0, 0);
        __syncthreads();   // LDS reads done before next overwrite
    }

    // epilogue: bias + fp16 store. C/D: col=lane&15, row=(lane>>4)*4+reg
    const int rq = (lane >> 4) * 4;
    float bval[4];
    #pragma unroll
    for (int n = 0; n < 4; ++n)
        bval[n] = bias[col0 + wcol + n * 16 + fr];
    #pragma unroll
    for (int m = 0; m < 4; ++m) {
        #pragma unroll
        for (int r = 0; r < 4; ++r) {
            const int row = row0 + wrow + m * 16 + rq + r;
            _Float16* op = O + (size_t)row * CDIM + col0 + wcol + fr;
            #pragma unroll
            for (int n = 0; n < 4; ++n)
                op[n * 16] = (_Float16)(acc[m][n][r] + bval[n]);
        }
    }
}

// ---------------------------------------------------------------------------
// k row L2-normalization in-place (fp16), one wave per token
// ---------------------------------------------------------------------------
__global__ __launch_bounds__(256) void knorm_f16(_Float16* __restrict__ k)
{
    const int tok  = blockIdx.x * 4 + (threadIdx.x >> 6);
    const int lane = threadIdx.x & 63;
    _Float16* p = k + (size_t)tok * CDIM + lane * 8;
    half8 v = *(const half8*)p;
    float s = 0.f;
    #pragma unroll
    for (int e = 0; e < 8; ++e) {
        const float f = (float)v[e];
        s = fmaf(f, f, s);
    }
    s = wave_sum64(s);
    const float scale = 1.f / fmaxf(sqrtf(s), 1e-12f);
    #pragma unroll
    for (int e = 0; e < 8; ++e)
        v[e] = (_Float16)((float)v[e] * scale);
    *(half8*)p = v;
}

// ---------------------------------------------------------------------------
// Local attention v2: ONE WAVE PER WINDOW, 4 windows per 256-thread block.
// Zero LDS, zero barriers -> clean 4-wave blocks, 8 blocks/CU at <=64 VGPR.
// Lane owns 8 channels; per q-row: 14 dot reductions (wave_sum64), softmax
// redundant in-register, online PV, immediate store. k/v re-reads served by
// L1/L2 (28 KB window working set). k pre-normalized. self=-5e4,
// causal/pad=-FLT_MAX. All loads unconditional: "invalid" j addresses land
// in adjacent ws regions (real fp16 data, no NaN), masked in softmax.
// ---------------------------------------------------------------------------
__global__ __launch_bounds__(256) void local_attn_f16(
    const _Float16* __restrict__ q,
    const _Float16* __restrict__ k,
    const _Float16* __restrict__ v,
    float* __restrict__ out)
{
    const int wave  = threadIdx.x >> 6;
    const int lane  = threadIdx.x & 63;
    const int gwin  = blockIdx.x * 4 + wave;      // global window 0..7167
    const int batch = gwin / NWIN;
    const int win   = gwin % NWIN;
    const int c     = lane * 8;

    const long long tok0 = (long long)batch * NTOK_PER_B + (long long)win * 7;
    const _Float16* kbase = k + (tok0 - 7) * CDIM + c;
    const _Float16* vbase = v + (tok0 - 7) * CDIM + c;
    const bool w0 = (win == 0);   // wave-uniform

    for (int i = 0; i < 7; ++i) {
        const half8 q8 = *(const half8*)(q + (tok0 + i) * CDIM + c);

        // 14 dot products, wave-reduced (independent chains -> ILP)
        float dots[14];
        #pragma unroll
        for (int j = 0; j < 14; ++j) {
            const half8 k8 = *(const half8*)(kbase + j * CDIM);
            float d = 0.f;
            #pragma unroll
            for (int e = 0; e < 8; ++e)
                d = fmaf((float)q8[e], (float)k8[e], d);
            dots[j] = d;
        }
        #pragma unroll
        for (int j = 0; j < 14; ++j)
            dots[j] = wave_sum64(dots[j]);

        // mask + softmax (redundant across lanes, in-register)
        float sc[14];
        #pragma unroll
        for (int j = 0; j < 14; ++j) {
            if (j > i + 7 || (w0 && j < 7)) sc[j] = -3.402823466e38f;
            else if (j == i + 7)            sc[j] = -5e4f;
            else                            sc[j] = dots[j] * SCALE;
        }
        float m = sc[0];
        #pragma unroll
        for (int j = 1; j < 14; ++j) m = fmaxf(m, sc[j]);
        float sum = 0.f;
        #pragma unroll
        for (int j = 0; j < 14; ++j) {
            sc[j] = __expf(sc[j] - m);
            sum += sc[j];
        }
        const float inv = 1.f / sum;

        // online PV for this row
        float o[8];
        #pragma unroll
        for (int e = 0; e < 8; ++e) o[e] = 0.f;
        #pragma unroll
        for (int j = 0; j < 14; ++j) {
            const half8 v8 = *(const half8*)(vbase + j * CDIM);
            const float a = sc[j] * inv;
            #pragma unroll
            for (int e = 0; e < 8; ++e)
                o[e] = fmaf(a, (float)v8[e], o[e]);
        }

        float* op = out + (tok0 + i) * CDIM + c;
        *(float4*)(op)     = make_float4(o[0], o[1], o[2], o[3]);
        *(float4*)(op + 4) = make_float4(o[4], o[5], o[6], o[7]);
    }
}

// ---------------------------------------------------------------------------
extern "C" void kernel_launch(void* const* d_in, const int* in_sizes, int n_in,
                              void* d_out, int out_size, void* d_ws, size_t ws_size,
                              hipStream_t stream)
{
    const float* x  = (const float*)d_in[0];
    const float* wq = (const float*)d_in[1];
    const float* bq = (const float*)d_in[2];
    const float* wk = (const float*)d_in[3];
    const float* bk = (const float*)d_in[4];
    const float* wv = (const float*)d_in[5];
    const float* bv = (const float*)d_in[6];
    float* out = (float*)d_out;

    char* ws = (char*)d_ws;
    const size_t XH_BYTES = (size_t)M_TOK * CDIM * sizeof(_Float16);   // 51.4 MB
    const size_t WT_BYTES = (size_t)3 * CDIM * CDIM * sizeof(_Float16);
    _Float16* xh  = (_Float16*)ws;
    _Float16* wt  = (_Float16*)(ws + XH_BYTES);
    _Float16* qkv = (_Float16*)(ws + XH_BYTES + WT_BYTES);
    _Float16* qh = qkv;
    _Float16* kh = qkv + (size_t)M_TOK * CDIM;
    _Float16* vh = kh  + (size_t)M_TOK * CDIM;

    cvt_f32_f16<<<12544, 256, 0, stream>>>(x, xh);
    cvt_w_t<<<dim3(16, 16, 3), 256, 0, stream>>>(wq, wk, wv, wt);
    qkv_gemm_f16<<<dim3(M_TOK / 128, CDIM / 128, 3), 256, 0, stream>>>(
        xh, wt, bq, bk, bv, qkv);
    knorm_f16<<<M_TOK / 4, 256, 0, stream>>>(kh);
    local_attn_f16<<<(NBATCH * NWIN) / 4, 256, 0, stream>>>(qh, kh, vh, out);
}

// Round 7
// 366.923 us; speedup vs baseline: 1.3470x; 1.3470x over previous
//
#include <hip/hip_runtime.h>
#include <math.h>

// Problem constants (B=16, H=W=56, C=512, window=7)
#define NTOK_PER_B 3136
#define NBATCH 16
#define M_TOK (NTOK_PER_B * NBATCH)   // 50176
#define CDIM 512
#define NWIN 448                      // 3136 / 7
#define SCALE 0.04419417382415922f    // 512^-0.5

typedef _Float16 half8 __attribute__((ext_vector_type(8)));
typedef float f32x4 __attribute__((ext_vector_type(4)));
typedef float f32x2 __attribute__((ext_vector_type(2)));

#define GLOAD16(g, l) __builtin_amdgcn_global_load_lds( \
    (const __attribute__((address_space(1))) void*)(g),  \
    (__attribute__((address_space(3))) void*)(l), 16, 0, 0)

__device__ __forceinline__ float wave_sum64(float s) {
    #pragma unroll
    for (int o = 32; o >= 1; o >>= 1) s += __shfl_xor(s, o, 64);
    return s;
}

// ---------------------------------------------------------------------------
// x (fp32) -> fp16, 8 elems/thread
// ---------------------------------------------------------------------------
__global__ __launch_bounds__(256) void cvt_f32_f16(
    const float* __restrict__ x, _Float16* __restrict__ y)
{
    const size_t i = ((size_t)blockIdx.x * 256 + threadIdx.x) * 8;
    const float4 a = *(const float4*)(x + i);
    const float4 b = *(const float4*)(x + i + 4);
    half8 o;
    o[0] = (_Float16)a.x; o[1] = (_Float16)a.y; o[2] = (_Float16)a.z; o[3] = (_Float16)a.w;
    o[4] = (_Float16)b.x; o[5] = (_Float16)b.y; o[6] = (_Float16)b.z; o[7] = (_Float16)b.w;
    *(half8*)(y + i) = o;
}

// ---------------------------------------------------------------------------
// W [K=512][N=512] fp32 -> Wt [N][K] fp16 (transposed), 3 matrices via z
// ---------------------------------------------------------------------------
__global__ __launch_bounds__(256) void cvt_w_t(
    const float* __restrict__ w0, const float* __restrict__ w1,
    const float* __restrict__ w2, _Float16* __restrict__ wt)
{
    const float* w = (blockIdx.z == 0) ? w0 : ((blockIdx.z == 1) ? w1 : w2);
    _Float16* o = wt + (size_t)blockIdx.z * CDIM * CDIM;
    __shared__ float tile[32][33];
    const int tx = threadIdx.x & 31;
    const int ty = threadIdx.x >> 5;          // 0..7
    const int k0 = blockIdx.x * 32;
    const int n0 = blockIdx.y * 32;
    #pragma unroll
    for (int r = 0; r < 32; r += 8)
        tile[ty + r][tx] = w[(size_t)(k0 + ty + r) * CDIM + n0 + tx];
    __syncthreads();
    #pragma unroll
    for (int r = 0; r < 32; r += 8)
        o[(size_t)(n0 + ty + r) * CDIM + k0 + tx] = (_Float16)tile[tx][ty + r];
}

// ---------------------------------------------------------------------------
// GEMM (R2-measured structure): out[z] = xh @ Wt[z]^T + bias.
// 128x128 tile, BK=32, 4 waves (2x2), 4x4 16x16x32 MFMA frags.
// grid = (392, 4, 3)
// ---------------------------------------------------------------------------
__global__ __launch_bounds__(256) void qkv_gemm_f16(
    const _Float16* __restrict__ A,
    const _Float16* __restrict__ Wt,
    const float* __restrict__ b0, const float* __restrict__ b1,
    const float* __restrict__ b2,
    _Float16* __restrict__ out)
{
    const int z = blockIdx.z;
    const _Float16* W = Wt + (size_t)z * CDIM * CDIM;
    const float* bias = (z == 0) ? b0 : ((z == 1) ? b1 : b2);
    _Float16* O = out + (size_t)z * (size_t)M_TOK * CDIM;

    __shared__ _Float16 As[128 * 32];   // row-major [row][k]
    __shared__ _Float16 Bs[128 * 32];   // row-major [n][k]

    const int t    = threadIdx.x;
    const int lane = t & 63;
    const int wid  = t >> 6;
    const int wrow = (wid >> 1) * 64;
    const int wcol = (wid & 1) * 64;
    const int row0 = blockIdx.x * 128;
    const int col0 = blockIdx.y * 128;

    const _Float16* aSrc0 = A + (size_t)(row0 + (t >> 2)) * CDIM + (t & 3) * 8;
    const _Float16* aSrc1 = aSrc0 + (size_t)64 * CDIM;
    const _Float16* bSrc0 = W + (size_t)(col0 + (t >> 2)) * CDIM + (t & 3) * 8;
    const _Float16* bSrc1 = bSrc0 + (size_t)64 * CDIM;
    _Float16* aDst0 = As + t * 8;
    _Float16* aDst1 = As + (t + 256) * 8;
    _Float16* bDst0 = Bs + t * 8;
    _Float16* bDst1 = Bs + (t + 256) * 8;

    f32x4 acc[4][4];
    #pragma unroll
    for (int m = 0; m < 4; ++m)
        #pragma unroll
        for (int n = 0; n < 4; ++n)
            acc[m][n] = (f32x4){0.f, 0.f, 0.f, 0.f};

    const int fr  = lane & 15;
    const int q8o = (lane >> 4) * 8;

    for (int k0 = 0; k0 < CDIM; k0 += 32) {
        GLOAD16(aSrc0 + k0, aDst0);
        GLOAD16(aSrc1 + k0, aDst1);
        GLOAD16(bSrc0 + k0, bDst0);
        GLOAD16(bSrc1 + k0, bDst1);
        __syncthreads();   // drains vmcnt: LDS tile ready

        half8 af[4], bf[4];
        #pragma unroll
        for (int m = 0; m < 4; ++m)
            af[m] = *(const half8*)(As + (wrow + m * 16 + fr) * 32 + q8o);
        #pragma unroll
        for (int n = 0; n < 4; ++n)
            bf[n] = *(const half8*)(Bs + (wcol + n * 16 + fr) * 32 + q8o);
        #pragma unroll
        for (int m = 0; m < 4; ++m)
            #pragma unroll
            for (int n = 0; n < 4; ++n)
                acc[m][n] = __builtin_amdgcn_mfma_f32_16x16x32_f16(
                    af[m], bf[n], acc[m][n], 0, 0, 0);
        __syncthreads();   // LDS reads done before next overwrite
    }

    const int rq = (lane >> 4) * 4;
    float bval[4];
    #pragma unroll
    for (int n = 0; n < 4; ++n)
        bval[n] = bias[col0 + wcol + n * 16 + fr];
    #pragma unroll
    for (int m = 0; m < 4; ++m) {
        #pragma unroll
        for (int r = 0; r < 4; ++r) {
            const int row = row0 + wrow + m * 16 + rq + r;
            _Float16* op = O + (size_t)row * CDIM + col0 + wcol + fr;
            #pragma unroll
            for (int n = 0; n < 4; ++n)
                op[n * 16] = (_Float16)(acc[m][n][r] + bval[n]);
        }
    }
}

// ---------------------------------------------------------------------------
// k row L2-normalization in-place (fp16), one wave per token
// ---------------------------------------------------------------------------
__global__ __launch_bounds__(256) void knorm_f16(_Float16* __restrict__ k)
{
    const int tok  = blockIdx.x * 4 + (threadIdx.x >> 6);
    const int lane = threadIdx.x & 63;
    _Float16* p = k + (size_t)tok * CDIM + lane * 8;
    half8 v = *(const half8*)p;
    float s = 0.f;
    #pragma unroll
    for (int e = 0; e < 8; ++e) {
        const float f = (float)v[e];
        s = fmaf(f, f, s);
    }
    s = wave_sum64(s);
    const float scale = 1.f / fmaxf(sqrtf(s), 1e-12f);
    #pragma unroll
    for (int e = 0; e < 8; ++e)
        v[e] = (_Float16)((float)v[e] * scale);
    *(half8*)p = v;
}

// ---------------------------------------------------------------------------
// Local attention v3 (MFMA QK^T): one wave per window, 4 windows/block.
// QK^T = one 16x16x32 f16 MFMA chain over K=512: A rows = 7 q-rows (pad 16),
// B cols = 14 keys (pad 16). Fragments loaded directly from global
// (lanes {l,l+16,l+32,l+48} read 64B contiguous of one token row).
// Softmax: 16-lane shfl_xor reductions (4+4 steps per row-reg).
// P -> per-wave LDS tile (same-wave RAW, lgkmcnt(0), no barrier) -> coalesced
// VALU PV with v held in registers. All token indices clamped in-bounds;
// padded rows/cols masked. self=-5e4, causal/pad=-FLT_MAX. k pre-normalized.
// ---------------------------------------------------------------------------
__global__ __launch_bounds__(256) void local_attn_mfma(
    const _Float16* __restrict__ q,
    const _Float16* __restrict__ k,
    const _Float16* __restrict__ v,
    float* __restrict__ out)
{
    const int wave = threadIdx.x >> 6;
    const int lane = threadIdx.x & 63;
    const int gwin = blockIdx.x * 4 + wave;   // 0..7167
    const int batch = gwin / NWIN;
    const int win   = gwin % NWIN;

    __shared__ float attnw[4][16][16];

    const long long tok0 = (long long)batch * NTOK_PER_B + (long long)win * 7;

    const int fr = lane & 15;        // A-row (q row) / B-col (key) / C-col
    const int ko = (lane >> 4) * 8;  // fragment k-offset (halfs)

    // ---- QK^T: 16 MFMAs over K=512 ----
    long long tokA = tok0 + fr;                        // rows 7..15 = padding
    if (tokA > (long long)M_TOK - 1) tokA = M_TOK - 1;
    long long tokB = tok0 - 7 + fr;                    // keys 14,15 = padding
    if (tokB < 0) tokB = 0;
    if (tokB > (long long)M_TOK - 1) tokB = M_TOK - 1;
    const _Float16* aptr = q + tokA * CDIM + ko;
    const _Float16* bptr = k + tokB * CDIM + ko;

    f32x4 acc = (f32x4){0.f, 0.f, 0.f, 0.f};
    #pragma unroll
    for (int k0 = 0; k0 < CDIM; k0 += 32) {
        const half8 af = *(const half8*)(aptr + k0);
        const half8 bf = *(const half8*)(bptr + k0);
        acc = __builtin_amdgcn_mfma_f32_16x16x32_f16(af, bf, acc, 0, 0, 0);
    }
    // acc[r] = S[row = (lane>>4)*4 + r][col = fr]

    // ---- mask + softmax over 16-lane groups ----
    const int g = lane >> 4;
    const int j = fr;
    const bool w0 = (win == 0);
    #pragma unroll
    for (int r = 0; r < 4; ++r) {
        const int i = g * 4 + r;
        float s;
        if (i >= 7 || j >= 14 || j > i + 7 || (w0 && j < 7))
            s = -3.402823466e38f;          // padding / causal / window-pad
        else if (j == i + 7)
            s = -5e4f;                      // shared-qk self token
        else
            s = acc[r] * SCALE;
        float m = s;
        m = fmaxf(m, __shfl_xor(m, 1, 64));
        m = fmaxf(m, __shfl_xor(m, 2, 64));
        m = fmaxf(m, __shfl_xor(m, 4, 64));
        m = fmaxf(m, __shfl_xor(m, 8, 64));
        float e = __expf(s - m);
        float sum = e;
        sum += __shfl_xor(sum, 1, 64);
        sum += __shfl_xor(sum, 2, 64);
        sum += __shfl_xor(sum, 4, 64);
        sum += __shfl_xor(sum, 8, 64);
        attnw[wave][i][j] = e / sum;        // rows >=7 are garbage, never read
    }
    asm volatile("s_waitcnt lgkmcnt(0)" ::: "memory");  // same-wave RAW on LDS

    // ---- PV: coalesced, v in registers, P broadcast from LDS ----
    const int c = lane * 8;
    half8 v8[14];
    #pragma unroll
    for (int jj = 0; jj < 14; ++jj) {
        long long tv = tok0 - 7 + jj;
        if (tv < 0) tv = 0;                 // garbage, P==0 for masked j
        v8[jj] = *(const half8*)(v + tv * CDIM + c);
    }
    #pragma unroll
    for (int i = 0; i < 7; ++i) {
        const f32x4 a0 = *(const f32x4*)&attnw[wave][i][0];
        const f32x4 a1 = *(const f32x4*)&attnw[wave][i][4];
        const f32x4 a2 = *(const f32x4*)&attnw[wave][i][8];
        const f32x2 a3 = *(const f32x2*)&attnw[wave][i][12];
        float aw[14] = {a0[0], a0[1], a0[2], a0[3],
                        a1[0], a1[1], a1[2], a1[3],
                        a2[0], a2[1], a2[2], a2[3],
                        a3[0], a3[1]};
        float o[8];
        #pragma unroll
        for (int e = 0; e < 8; ++e) o[e] = 0.f;
        #pragma unroll
        for (int jj = 0; jj < 14; ++jj) {
            #pragma unroll
            for (int e = 0; e < 8; ++e)
                o[e] = fmaf(aw[jj], (float)v8[jj][e], o[e]);
        }
        float* op = out + (tok0 + i) * CDIM + c;
        *(float4*)(op)     = make_float4(o[0], o[1], o[2], o[3]);
        *(float4*)(op + 4) = make_float4(o[4], o[5], o[6], o[7]);
    }
}

// ---------------------------------------------------------------------------
extern "C" void kernel_launch(void* const* d_in, const int* in_sizes, int n_in,
                              void* d_out, int out_size, void* d_ws, size_t ws_size,
                              hipStream_t stream)
{
    const float* x  = (const float*)d_in[0];
    const float* wq = (const float*)d_in[1];
    const float* bq = (const float*)d_in[2];
    const float* wk = (const float*)d_in[3];
    const float* bk = (const float*)d_in[4];
    const float* wv = (const float*)d_in[5];
    const float* bv = (const float*)d_in[6];
    float* out = (float*)d_out;

    char* ws = (char*)d_ws;
    const size_t XH_BYTES = (size_t)M_TOK * CDIM * sizeof(_Float16);   // 51.4 MB
    const size_t WT_BYTES = (size_t)3 * CDIM * CDIM * sizeof(_Float16);
    _Float16* xh  = (_Float16*)ws;
    _Float16* wt  = (_Float16*)(ws + XH_BYTES);
    _Float16* qkv = (_Float16*)(ws + XH_BYTES + WT_BYTES);
    _Float16* qh = qkv;
    _Float16* kh = qkv + (size_t)M_TOK * CDIM;
    _Float16* vh = kh  + (size_t)M_TOK * CDIM;

    cvt_f32_f16<<<12544, 256, 0, stream>>>(x, xh);
    cvt_w_t<<<dim3(16, 16, 3), 256, 0, stream>>>(wq, wk, wv, wt);
    qkv_gemm_f16<<<dim3(M_TOK / 128, CDIM / 128, 3), 256, 0, stream>>>(
        xh, wt, bq, bk, bv, qkv);
    knorm_f16<<<M_TOK / 4, 256, 0, stream>>>(kh);
    local_attn_mfma<<<(NBATCH * NWIN) / 4, 256, 0, stream>>>(qh, kh, vh, out);
}